// Round 6
// baseline (1529.396 us; speedup 1.0000x reference)
//
#include <hip/hip_runtime.h>

// TemporalGCN: 2x GCNConv(64->64) + relu, global_mean_pool(64 graphs), linear 64->64.
// R4 design: NO sorted CSR (random 4B final-placement writes were 67MB of HBM
// writeback for 6.4MB payload). Instead:
//   part_kernel:  edges -> 782 buckets of 128 dst-nodes, packed u32 (src|dlow<<24)
//   deg_dinv:     per-bucket LDS histogram -> dinv
//   gemm_scale:   y = (x@W)*dinv  (float4 LDS tile)
//   agg_kernel:   per-bucket LDS float accumulator, ds_add_f32, coalesced H write
//   pool/final:   unchanged

#define DF 64
#define BSH 7                 // bucket = 128 consecutive dst nodes
#define BNODES 128
#define CAP 4096              // per-bucket edge capacity (mean 2048, +45 sigma)
#define ASTRIDE 65            // LDS acc row stride (floats) - spreads banks

// ---------------- P1: partition edges into dst/128 buckets ----------------

__global__ __launch_bounds__(256) void part_kernel(
        const int* __restrict__ src, const int* __restrict__ dst,
        const int4* __restrict__ src4, const int4* __restrict__ dst4,
        int E, unsigned* __restrict__ bedges, int* __restrict__ bucketCur, int nb) {
    __shared__ int lcnt[1024];
    __shared__ int lbase[1024];
    int tid = threadIdx.x;
    for (int t = tid; t < nb; t += 256) lcnt[t] = 0;
    __syncthreads();
    int nq = E >> 2;
    unsigned packed[32];
    int bkt[32];
    int rk[32];
    int qbase = blockIdx.x * 2048;
#pragma unroll
    for (int c = 0; c < 8; c++) {
        int qi = qbase + c * 256 + tid;
        int4 s = {0, 0, 0, 0}, d = {0, 0, 0, 0};
        bool v = qi < nq;
        if (v) { s = src4[qi]; d = dst4[qi]; }
        packed[4*c+0] = (unsigned)s.x | ((unsigned)(d.x & (BNODES-1)) << 24);
        packed[4*c+1] = (unsigned)s.y | ((unsigned)(d.y & (BNODES-1)) << 24);
        packed[4*c+2] = (unsigned)s.z | ((unsigned)(d.z & (BNODES-1)) << 24);
        packed[4*c+3] = (unsigned)s.w | ((unsigned)(d.w & (BNODES-1)) << 24);
        bkt[4*c+0] = v ? (d.x >> BSH) : -1;
        bkt[4*c+1] = v ? (d.y >> BSH) : -1;
        bkt[4*c+2] = v ? (d.z >> BSH) : -1;
        bkt[4*c+3] = v ? (d.w >> BSH) : -1;
    }
#pragma unroll
    for (int j = 0; j < 32; j++)
        rk[j] = (bkt[j] >= 0) ? atomicAdd(&lcnt[bkt[j]], 1) : 0;
    __syncthreads();
    for (int t = tid; t < nb; t += 256)
        lbase[t] = lcnt[t] ? atomicAdd(&bucketCur[t], lcnt[t]) : 0;
    __syncthreads();
#pragma unroll
    for (int j = 0; j < 32; j++) {
        if (bkt[j] >= 0) {
            int pos = lbase[bkt[j]] + rk[j];
            if (pos < CAP) bedges[(size_t)bkt[j] * CAP + pos] = packed[j];
        }
    }
    // tail edges (E not multiple of 4): handled once by block 0
    if (blockIdx.x == 0 && tid < (E & 3)) {
        int e = nq * 4 + tid;
        int sv = src[e], dv = dst[e];
        int b = dv >> BSH;
        int pos = atomicAdd(&bucketCur[b], 1);
        if (pos < CAP)
            bedges[(size_t)b * CAP + pos] =
                (unsigned)sv | ((unsigned)(dv & (BNODES-1)) << 24);
    }
}

// scalar fallback for unaligned edge_index (not expected in practice)
__global__ void part_scalar_kernel(const int* __restrict__ src, const int* __restrict__ dst,
                                   int E, unsigned* __restrict__ bedges,
                                   int* __restrict__ bucketCur) {
    int stride = gridDim.x * blockDim.x;
    for (int e = blockIdx.x * blockDim.x + threadIdx.x; e < E; e += stride) {
        int sv = src[e], dv = dst[e];
        int b = dv >> BSH;
        int pos = atomicAdd(&bucketCur[b], 1);
        if (pos < CAP)
            bedges[(size_t)b * CAP + pos] =
                (unsigned)sv | ((unsigned)(dv & (BNODES-1)) << 24);
    }
}

// ---------------- P2: per-bucket degree -> dinv ----------------

__global__ void deg_dinv_kernel(const unsigned* __restrict__ bedges,
                                const int* __restrict__ bucketCur,
                                float* __restrict__ dinv, int N) {
    __shared__ int cnt[BNODES];
    int b = blockIdx.x, tid = threadIdx.x;
    if (tid < BNODES) cnt[tid] = 0;
    __syncthreads();
    int n = min(bucketCur[b], CAP);
    const unsigned* p = bedges + (size_t)b * CAP;
    for (int i = tid; i < n; i += 256) atomicAdd(&cnt[p[i] >> 24], 1);
    __syncthreads();
    int node = (b << BSH) + tid;
    if (tid < BNODES && node < N)
        dinv[node] = 1.0f / sqrtf((float)(cnt[tid] + 1));  // deg = in + self-loop
}

// ---------------- per-layer compute ----------------

// Y[row][c] = (sum_k X[row][k] * W[k][c]) * dinv[row]; float4 per thread.
__global__ void gemm_scale(const float4* __restrict__ X4, const float4* __restrict__ W4,
                           const float* __restrict__ dinv, float4* __restrict__ Y4, int n) {
    __shared__ float4 Wl4[64][16];   // [k][c4]
    __shared__ float Xl[16][68];     // padded: conflict-free broadcast
    int tid = threadIdx.x;
    float4* Wf = &Wl4[0][0];
#pragma unroll
    for (int i = 0; i < 4; i++) {
        int idx = tid + i * 256;     // idx = k*16 + c4
        Wf[idx] = W4[idx];
    }
    int row0 = blockIdx.x * 16;
    int r = tid >> 4, c4 = tid & 15;
    {
        int row = row0 + r;
        float4 v = (row < n) ? X4[(size_t)row * 16 + c4] : float4{0.f, 0.f, 0.f, 0.f};
        Xl[r][c4 * 4 + 0] = v.x;
        Xl[r][c4 * 4 + 1] = v.y;
        Xl[r][c4 * 4 + 2] = v.z;
        Xl[r][c4 * 4 + 3] = v.w;
    }
    __syncthreads();
    float ax = 0.f, ay = 0.f, az = 0.f, aw = 0.f;
#pragma unroll
    for (int k = 0; k < 64; k++) {
        float xv = Xl[r][k];
        float4 w = Wl4[k][c4];
        ax += xv * w.x;
        ay += xv * w.y;
        az += xv * w.z;
        aw += xv * w.w;
    }
    int row = row0 + r;
    if (row < n) {
        float dv = dinv[row];
        Y4[(size_t)row * 16 + c4] = float4{ax * dv, ay * dv, az * dv, aw * dv};
    }
}

// H[node][:] = relu(dinv*(acc + y_self) + b), acc accumulated in LDS.
// One block per 128-node bucket; 512 threads = 32 groups of 16 lanes, float4/lane.
__global__ __launch_bounds__(512) void agg_kernel(
        const float4* __restrict__ Y4, const unsigned* __restrict__ bedges,
        const int* __restrict__ bucketCur, const float* __restrict__ dinv,
        const float4* __restrict__ bias4, float4* __restrict__ H4, int N) {
    __shared__ float acc[BNODES * ASTRIDE];
    int tid = threadIdx.x;
    for (int i = tid; i < BNODES * ASTRIDE; i += 512) acc[i] = 0.f;
    __syncthreads();
    int b = blockIdx.x;
    int cnt = min(bucketCur[b], CAP);
    const unsigned* ep = bedges + (size_t)b * CAP;
    int gg = tid >> 4;        // group 0..31
    int q = tid & 15;
    int q4 = q * 4;
    int i = gg;
    for (; i + 96 < cnt; i += 128) {
        unsigned u0 = ep[i];
        unsigned u1 = ep[i + 32];
        unsigned u2 = ep[i + 64];
        unsigned u3 = ep[i + 96];
        float4 v0 = Y4[(size_t)(u0 & 0xFFFFFFu) * 16 + q];
        float4 v1 = Y4[(size_t)(u1 & 0xFFFFFFu) * 16 + q];
        float4 v2 = Y4[(size_t)(u2 & 0xFFFFFFu) * 16 + q];
        float4 v3 = Y4[(size_t)(u3 & 0xFFFFFFu) * 16 + q];
        int a0 = (int)(u0 >> 24) * ASTRIDE + q4;
        int a1 = (int)(u1 >> 24) * ASTRIDE + q4;
        int a2 = (int)(u2 >> 24) * ASTRIDE + q4;
        int a3 = (int)(u3 >> 24) * ASTRIDE + q4;
        atomicAdd(&acc[a0], v0.x); atomicAdd(&acc[a0+1], v0.y);
        atomicAdd(&acc[a0+2], v0.z); atomicAdd(&acc[a0+3], v0.w);
        atomicAdd(&acc[a1], v1.x); atomicAdd(&acc[a1+1], v1.y);
        atomicAdd(&acc[a1+2], v1.z); atomicAdd(&acc[a1+3], v1.w);
        atomicAdd(&acc[a2], v2.x); atomicAdd(&acc[a2+1], v2.y);
        atomicAdd(&acc[a2+2], v2.z); atomicAdd(&acc[a2+3], v2.w);
        atomicAdd(&acc[a3], v3.x); atomicAdd(&acc[a3+1], v3.y);
        atomicAdd(&acc[a3+2], v3.z); atomicAdd(&acc[a3+3], v3.w);
    }
    for (; i < cnt; i += 32) {
        unsigned u = ep[i];
        float4 v = Y4[(size_t)(u & 0xFFFFFFu) * 16 + q];
        int a = (int)(u >> 24) * ASTRIDE + q4;
        atomicAdd(&acc[a], v.x); atomicAdd(&acc[a+1], v.y);
        atomicAdd(&acc[a+2], v.z); atomicAdd(&acc[a+3], v.w);
    }
    __syncthreads();
    float4 bq = bias4[q];
    int r0 = tid >> 4;
#pragma unroll
    for (int p = 0; p < 4; p++) {
        int r = r0 + p * 32;
        int node = (b << BSH) + r;
        if (node < N) {
            float4 self = Y4[(size_t)node * 16 + q];
            float dv = dinv[node];
            int a = r * ASTRIDE + q4;
            float4 o;
            o.x = fmaxf(dv * (acc[a]     + self.x) + bq.x, 0.f);
            o.y = fmaxf(dv * (acc[a + 1] + self.y) + bq.y, 0.f);
            o.z = fmaxf(dv * (acc[a + 2] + self.z) + bq.z, 0.f);
            o.w = fmaxf(dv * (acc[a + 3] + self.w) + bq.w, 0.f);
            H4[(size_t)node * 16 + q] = o;
        }
    }
}

// ---------------- pooling + head ----------------

__global__ void pool_kernel(const float4* __restrict__ H4, const int* __restrict__ batch,
                            float* __restrict__ sums, int* __restrict__ cnts, int n) {
    int gw = (blockIdx.x * blockDim.x + threadIdx.x) >> 6;
    int lane = threadIdx.x & 63;
    int g = lane >> 4, q = lane & 15;
    int start = gw * 256;
    if (start >= n) return;
    int end = min(start + 256, n);
    float ax = 0.f, ay = 0.f, az = 0.f, aw = 0.f;
    int cur = -1, run = 0;
    for (int i = start + g; i < end; i += 4) {
        int b = batch[i];
        if (b != cur) {
            if (run > 0) {
                atomicAdd(&sums[cur * DF + q * 4 + 0], ax);
                atomicAdd(&sums[cur * DF + q * 4 + 1], ay);
                atomicAdd(&sums[cur * DF + q * 4 + 2], az);
                atomicAdd(&sums[cur * DF + q * 4 + 3], aw);
                if (q == 0) atomicAdd(&cnts[cur], run);
            }
            cur = b; run = 0;
            ax = ay = az = aw = 0.f;
        }
        float4 v = H4[(size_t)i * 16 + q];
        ax += v.x; ay += v.y; az += v.z; aw += v.w;
        run++;
    }
    if (run > 0) {
        atomicAdd(&sums[cur * DF + q * 4 + 0], ax);
        atomicAdd(&sums[cur * DF + q * 4 + 1], ay);
        atomicAdd(&sums[cur * DF + q * 4 + 2], az);
        atomicAdd(&sums[cur * DF + q * 4 + 3], aw);
        if (q == 0) atomicAdd(&cnts[cur], run);
    }
}

__global__ void final_kernel(const float* __restrict__ sums, const int* __restrict__ cnts,
                             const float* __restrict__ Wp, const float* __restrict__ bp,
                             float* __restrict__ out) {
    int g = blockIdx.x, j = threadIdx.x;
    __shared__ float hg[64];
    float c = fmaxf((float)cnts[g], 1.f);
    hg[j] = sums[g * DF + j] / c;
    __syncthreads();
    float acc = bp[j];
#pragma unroll
    for (int k = 0; k < 64; k++) acc += hg[k] * Wp[k * DF + j];
    out[g * DF + j] = acc;
}

// ---------------- launch ----------------

extern "C" void kernel_launch(void* const* d_in, const int* in_sizes, int n_in,
                              void* d_out, int out_size, void* d_ws, size_t ws_size,
                              hipStream_t stream) {
    const float* x     = (const float*)d_in[0];
    const int*   ei    = (const int*)d_in[1];
    const int*   batch = (const int*)d_in[2];
    const float* W1    = (const float*)d_in[3];
    const float* b1    = (const float*)d_in[4];
    const float* W2    = (const float*)d_in[5];
    const float* b2    = (const float*)d_in[6];
    const float* Wp    = (const float*)d_in[7];
    const float* bp    = (const float*)d_in[8];

    int N = in_sizes[0] / DF;
    int E = in_sizes[1] / 2;
    const int* src = ei;
    const int* dst = ei + E;
    int NB = (N + BNODES - 1) >> BSH;     // buckets
    int quadOK = ((E & 3) == 0 || 1) && (((uintptr_t)ei & 15) == 0) && ((E * 4) % 16 == 0);

    char* ws = (char*)d_ws;
    auto alloc = [&](size_t bytes) {
        void* p = (void*)ws;
        ws += (bytes + 255) / 256 * 256;
        return p;
    };
    float*    dinv      = (float*)alloc((size_t)N * 4);
    int*      bucketCur = (int*)alloc((size_t)NB * 4);
    unsigned* bedges    = (unsigned*)alloc((size_t)NB * CAP * 4);
    float*    y         = (float*)alloc((size_t)N * DF * 4);
    float*    h         = (float*)alloc((size_t)N * DF * 4);
    float*    psums     = (float*)alloc(64 * DF * 4);   // 16 KB, 256-aligned
    int*      pcnt      = (int*)alloc(64 * 4);

    hipMemsetAsync(bucketCur, 0, (size_t)NB * 4, stream);
    hipMemsetAsync(psums, 0, 64 * DF * 4 + 256, stream);  // sums + cnts contiguous

    if (quadOK) {
        int nq = E >> 2;
        int pblocks = (nq + 2047) / 2048;
        part_kernel<<<pblocks, 256, 0, stream>>>(src, dst, (const int4*)src, (const int4*)dst,
                                                 E, bedges, bucketCur, NB);
    } else {
        part_scalar_kernel<<<1024, 256, 0, stream>>>(src, dst, E, bedges, bucketCur);
    }
    deg_dinv_kernel<<<NB, 256, 0, stream>>>(bedges, bucketCur, dinv, N);

    gemm_scale<<<(N + 15) / 16, 256, 0, stream>>>((const float4*)x, (const float4*)W1, dinv,
                                                  (float4*)y, N);
    agg_kernel<<<NB, 512, 0, stream>>>((const float4*)y, bedges, bucketCur, dinv,
                                       (const float4*)b1, (float4*)h, N);
    gemm_scale<<<(N + 15) / 16, 256, 0, stream>>>((const float4*)h, (const float4*)W2, dinv,
                                                  (float4*)y, N);
    agg_kernel<<<NB, 512, 0, stream>>>((const float4*)y, bedges, bucketCur, dinv,
                                       (const float4*)b2, (float4*)h, N);

    int waves = (N + 255) / 256;
    pool_kernel<<<(waves + 3) / 4, 256, 0, stream>>>((const float4*)h, batch, psums, pcnt, N);
    final_kernel<<<64, 64, 0, stream>>>(psums, pcnt, Wp, bp, (float*)d_out);
}

// Round 7
// 251.356 us; speedup vs baseline: 6.0846x; 6.0846x over previous
//
#include <hip/hip_runtime.h>
#include <hip/hip_fp16.h>

// TemporalGCN: 2x GCNConv(64->64) + relu, global_mean_pool(64 graphs), linear 64->64.
// R6: bucket partition (u32-packed edges) -> per-bucket LDS counting sort with
// NATIVE INT LDS atomics -> register-accumulated aggregation (NO float atomics
// anywhere; R4's fp32 LDS atomicAdd compiled to a CAS loop = 677us).
// y stored as fp16 (128B/row) to halve random-gather traffic; f32 accumulate.

#define DF 64
#define BSH 7                 // bucket = 128 consecutive dst nodes
#define BNODES 128
#define CAP 4096              // per-bucket edge capacity (mean 2048, >40 sigma)

struct alignas(8) h4 { __half2 a, b; };   // 4 halves = 8 bytes

// ---------------- P1: partition edges into dst/128 buckets ----------------

__global__ __launch_bounds__(256) void part_kernel(
        const int* __restrict__ src, const int* __restrict__ dst,
        const int4* __restrict__ src4, const int4* __restrict__ dst4,
        int E, unsigned* __restrict__ bedges, int* __restrict__ bucketCur, int nb) {
    __shared__ int lcnt[1024];
    __shared__ int lbase[1024];
    int tid = threadIdx.x;
    for (int t = tid; t < nb; t += 256) lcnt[t] = 0;
    __syncthreads();
    int nq = E >> 2;
    unsigned packed[32];
    int bkt[32];
    int rk[32];
    int qbase = blockIdx.x * 2048;
#pragma unroll
    for (int c = 0; c < 8; c++) {
        int qi = qbase + c * 256 + tid;
        int4 s = {0, 0, 0, 0}, d = {0, 0, 0, 0};
        bool v = qi < nq;
        if (v) { s = src4[qi]; d = dst4[qi]; }
        packed[4*c+0] = (unsigned)s.x | ((unsigned)(d.x & (BNODES-1)) << 24);
        packed[4*c+1] = (unsigned)s.y | ((unsigned)(d.y & (BNODES-1)) << 24);
        packed[4*c+2] = (unsigned)s.z | ((unsigned)(d.z & (BNODES-1)) << 24);
        packed[4*c+3] = (unsigned)s.w | ((unsigned)(d.w & (BNODES-1)) << 24);
        bkt[4*c+0] = v ? (d.x >> BSH) : -1;
        bkt[4*c+1] = v ? (d.y >> BSH) : -1;
        bkt[4*c+2] = v ? (d.z >> BSH) : -1;
        bkt[4*c+3] = v ? (d.w >> BSH) : -1;
    }
#pragma unroll
    for (int j = 0; j < 32; j++)
        rk[j] = (bkt[j] >= 0) ? atomicAdd(&lcnt[bkt[j]], 1) : 0;
    __syncthreads();
    for (int t = tid; t < nb; t += 256)
        lbase[t] = lcnt[t] ? atomicAdd(&bucketCur[t], lcnt[t]) : 0;
    __syncthreads();
#pragma unroll
    for (int j = 0; j < 32; j++) {
        if (bkt[j] >= 0) {
            int pos = lbase[bkt[j]] + rk[j];
            if (pos < CAP) bedges[(size_t)bkt[j] * CAP + pos] = packed[j];
        }
    }
    if (blockIdx.x == 0 && tid < (E & 3)) {
        int e = nq * 4 + tid;
        int sv = src[e], dv = dst[e];
        int b = dv >> BSH;
        int pos = atomicAdd(&bucketCur[b], 1);
        if (pos < CAP)
            bedges[(size_t)b * CAP + pos] =
                (unsigned)sv | ((unsigned)(dv & (BNODES-1)) << 24);
    }
}

__global__ void part_scalar_kernel(const int* __restrict__ src, const int* __restrict__ dst,
                                   int E, unsigned* __restrict__ bedges,
                                   int* __restrict__ bucketCur) {
    int stride = gridDim.x * blockDim.x;
    for (int e = blockIdx.x * blockDim.x + threadIdx.x; e < E; e += stride) {
        int sv = src[e], dv = dst[e];
        int b = dv >> BSH;
        int pos = atomicAdd(&bucketCur[b], 1);
        if (pos < CAP)
            bedges[(size_t)b * CAP + pos] =
                (unsigned)sv | ((unsigned)(dv & (BNODES-1)) << 24);
    }
}

// ------- P2: per-bucket LDS counting sort (int atomics only) + offsets + dinv -------

__global__ __launch_bounds__(256) void sort_kernel(
        unsigned* __restrict__ bedges, const int* __restrict__ bucketCur,
        int* __restrict__ offs, float* __restrict__ dinv, int N) {
    __shared__ unsigned ein[CAP];
    __shared__ unsigned eout[CAP];
    __shared__ int cnt[BNODES];
    __shared__ int sc[BNODES];
    __shared__ int off[BNODES + 1];
    __shared__ int cur[BNODES];
    int b = blockIdx.x, tid = threadIdx.x;
    int n = min(bucketCur[b], CAP);
    unsigned* gp = bedges + (size_t)b * CAP;
    if (tid < BNODES) cnt[tid] = 0;
    __syncthreads();
    for (int i = tid; i < n; i += 256) {
        unsigned u = gp[i];
        ein[i] = u;
        atomicAdd(&cnt[u >> 24], 1);      // native ds int atomic
    }
    __syncthreads();
    if (tid < BNODES) sc[tid] = cnt[tid];
    __syncthreads();
    for (int d = 1; d < BNODES; d <<= 1) {
        int v = (tid >= d && tid < BNODES) ? sc[tid - d] : 0;
        __syncthreads();
        if (tid < BNODES) sc[tid] += v;
        __syncthreads();
    }
    if (tid < BNODES) {
        off[tid + 1] = sc[tid];
        cur[tid] = sc[tid] - cnt[tid];
        if (tid == 0) off[0] = 0;
    }
    __syncthreads();
    for (int i = tid; i < n; i += 256) {
        unsigned u = ein[i];
        int p = atomicAdd(&cur[u >> 24], 1);
        eout[p] = u;
    }
    __syncthreads();
    for (int i = tid; i < n; i += 256) gp[i] = eout[i];
    if (tid <= BNODES) offs[(size_t)b * (BNODES + 1) + tid] = off[tid];
    int node = (b << BSH) + tid;
    if (tid < BNODES && node < N)
        dinv[node] = 1.0f / sqrtf((float)(cnt[tid] + 1));   // deg = in + self-loop
}

// ---------------- per-layer compute ----------------

// Y[row][c] = (sum_k X[row][k] * W[k][c]) * dinv[row]; fp16 output.
__global__ void gemm_scale(const float4* __restrict__ X4, const float4* __restrict__ W4,
                           const float* __restrict__ dinv, h4* __restrict__ Y2, int n) {
    __shared__ float4 Wl4[64][16];   // [k][c4]
    __shared__ float Xl[16][68];     // padded: conflict-free broadcast
    int tid = threadIdx.x;
    float4* Wf = &Wl4[0][0];
#pragma unroll
    for (int i = 0; i < 4; i++) {
        int idx = tid + i * 256;     // idx = k*16 + c4
        Wf[idx] = W4[idx];
    }
    int row0 = blockIdx.x * 16;
    int r = tid >> 4, c4 = tid & 15;
    {
        int row = row0 + r;
        float4 v = (row < n) ? X4[(size_t)row * 16 + c4] : float4{0.f, 0.f, 0.f, 0.f};
        Xl[r][c4 * 4 + 0] = v.x;
        Xl[r][c4 * 4 + 1] = v.y;
        Xl[r][c4 * 4 + 2] = v.z;
        Xl[r][c4 * 4 + 3] = v.w;
    }
    __syncthreads();
    float ax = 0.f, ay = 0.f, az = 0.f, aw = 0.f;
#pragma unroll
    for (int k = 0; k < 64; k++) {
        float xv = Xl[r][k];
        float4 w = Wl4[k][c4];
        ax += xv * w.x;
        ay += xv * w.y;
        az += xv * w.z;
        aw += xv * w.w;
    }
    int row = row0 + r;
    if (row < n) {
        float dv = dinv[row];
        h4 o;
        o.a = __floats2half2_rn(ax * dv, ay * dv);
        o.b = __floats2half2_rn(az * dv, aw * dv);
        Y2[(size_t)row * 16 + c4] = o;
    }
}

// H[node][:] = relu(dinv*(sum_edges y[src] + y[node]) + b).
// One block per HALF bucket (64 nodes); 256 thr = 16 groups x 16 lanes.
// Edges staged in LDS; per-group register accumulation, 4 gathers in flight.
__global__ __launch_bounds__(256) void agg_kernel(
        const h4* __restrict__ Y2, const unsigned* __restrict__ bedges,
        const int* __restrict__ offs, const float* __restrict__ dinv,
        const float4* __restrict__ bias4, float4* __restrict__ H4, int N) {
    __shared__ unsigned eb[CAP];
    __shared__ int off[65];
    int blk = blockIdx.x;
    int b = blk >> 1, half = blk & 1;
    int tid = threadIdx.x;
    if (tid < 65) off[tid] = offs[(size_t)b * (BNODES + 1) + half * 64 + tid];
    __syncthreads();
    int e0 = off[0];
    int ecnt = off[64] - e0;
    const unsigned* gp = bedges + (size_t)b * CAP + e0;
    for (int i = tid; i < ecnt; i += 256) eb[i] = gp[i];
    __syncthreads();
    int gg = tid >> 4, q = tid & 15;
    float4 bq = bias4[q];
    for (int r = gg; r < 64; r += 16) {
        int s = off[r] - e0, e = off[r + 1] - e0;
        float4 A0 = {0.f, 0.f, 0.f, 0.f}, A1 = A0, A2 = A0, A3 = A0;
        int i = s;
        for (; i + 3 < e; i += 4) {
            unsigned u0 = eb[i], u1 = eb[i + 1], u2 = eb[i + 2], u3 = eb[i + 3];
            h4 w0 = Y2[(size_t)(u0 & 0xFFFFFFu) * 16 + q];
            h4 w1 = Y2[(size_t)(u1 & 0xFFFFFFu) * 16 + q];
            h4 w2 = Y2[(size_t)(u2 & 0xFFFFFFu) * 16 + q];
            h4 w3 = Y2[(size_t)(u3 & 0xFFFFFFu) * 16 + q];
            float2 p0a = __half22float2(w0.a), p0b = __half22float2(w0.b);
            float2 p1a = __half22float2(w1.a), p1b = __half22float2(w1.b);
            float2 p2a = __half22float2(w2.a), p2b = __half22float2(w2.b);
            float2 p3a = __half22float2(w3.a), p3b = __half22float2(w3.b);
            A0.x += p0a.x; A0.y += p0a.y; A0.z += p0b.x; A0.w += p0b.y;
            A1.x += p1a.x; A1.y += p1a.y; A1.z += p1b.x; A1.w += p1b.y;
            A2.x += p2a.x; A2.y += p2a.y; A2.z += p2b.x; A2.w += p2b.y;
            A3.x += p3a.x; A3.y += p3a.y; A3.z += p3b.x; A3.w += p3b.y;
        }
        for (; i < e; i++) {
            unsigned u = eb[i];
            h4 w = Y2[(size_t)(u & 0xFFFFFFu) * 16 + q];
            float2 pa = __half22float2(w.a), pb = __half22float2(w.b);
            A0.x += pa.x; A0.y += pa.y; A0.z += pb.x; A0.w += pb.y;
        }
        int node = (b << BSH) + half * 64 + r;
        if (node < N) {
            float4 S;
            S.x = A0.x + A1.x + A2.x + A3.x;
            S.y = A0.y + A1.y + A2.y + A3.y;
            S.z = A0.z + A1.z + A2.z + A3.z;
            S.w = A0.w + A1.w + A2.w + A3.w;
            h4 sv = Y2[(size_t)node * 16 + q];
            float2 s1 = __half22float2(sv.a), s2 = __half22float2(sv.b);
            float dv = dinv[node];
            float4 o;
            o.x = fmaxf(dv * (S.x + s1.x) + bq.x, 0.f);
            o.y = fmaxf(dv * (S.y + s1.y) + bq.y, 0.f);
            o.z = fmaxf(dv * (S.z + s2.x) + bq.z, 0.f);
            o.w = fmaxf(dv * (S.w + s2.y) + bq.w, 0.f);
            H4[(size_t)node * 16 + q] = o;
        }
    }
}

// ---------------- pooling + head ----------------

__global__ void pool_kernel(const float4* __restrict__ H4, const int* __restrict__ batch,
                            float* __restrict__ sums, int* __restrict__ cnts, int n) {
    int gw = (blockIdx.x * blockDim.x + threadIdx.x) >> 6;
    int lane = threadIdx.x & 63;
    int g = lane >> 4, q = lane & 15;
    int start = gw * 256;
    if (start >= n) return;
    int end = min(start + 256, n);
    float ax = 0.f, ay = 0.f, az = 0.f, aw = 0.f;
    int cur = -1, run = 0;
    for (int i = start + g; i < end; i += 4) {
        int b = batch[i];
        if (b != cur) {
            if (run > 0) {
                atomicAdd(&sums[cur * DF + q * 4 + 0], ax);
                atomicAdd(&sums[cur * DF + q * 4 + 1], ay);
                atomicAdd(&sums[cur * DF + q * 4 + 2], az);
                atomicAdd(&sums[cur * DF + q * 4 + 3], aw);
                if (q == 0) atomicAdd(&cnts[cur], run);
            }
            cur = b; run = 0;
            ax = ay = az = aw = 0.f;
        }
        float4 v = H4[(size_t)i * 16 + q];
        ax += v.x; ay += v.y; az += v.z; aw += v.w;
        run++;
    }
    if (run > 0) {
        atomicAdd(&sums[cur * DF + q * 4 + 0], ax);
        atomicAdd(&sums[cur * DF + q * 4 + 1], ay);
        atomicAdd(&sums[cur * DF + q * 4 + 2], az);
        atomicAdd(&sums[cur * DF + q * 4 + 3], aw);
        if (q == 0) atomicAdd(&cnts[cur], run);
    }
}

__global__ void final_kernel(const float* __restrict__ sums, const int* __restrict__ cnts,
                             const float* __restrict__ Wp, const float* __restrict__ bp,
                             float* __restrict__ out) {
    int g = blockIdx.x, j = threadIdx.x;
    __shared__ float hg[64];
    float c = fmaxf((float)cnts[g], 1.f);
    hg[j] = sums[g * DF + j] / c;
    __syncthreads();
    float acc = bp[j];
#pragma unroll
    for (int k = 0; k < 64; k++) acc += hg[k] * Wp[k * DF + j];
    out[g * DF + j] = acc;
}

// ---------------- launch ----------------

extern "C" void kernel_launch(void* const* d_in, const int* in_sizes, int n_in,
                              void* d_out, int out_size, void* d_ws, size_t ws_size,
                              hipStream_t stream) {
    const float* x     = (const float*)d_in[0];
    const int*   ei    = (const int*)d_in[1];
    const int*   batch = (const int*)d_in[2];
    const float* W1    = (const float*)d_in[3];
    const float* b1    = (const float*)d_in[4];
    const float* W2    = (const float*)d_in[5];
    const float* b2    = (const float*)d_in[6];
    const float* Wp    = (const float*)d_in[7];
    const float* bp    = (const float*)d_in[8];

    int N = in_sizes[0] / DF;
    int E = in_sizes[1] / 2;
    const int* src = ei;
    const int* dst = ei + E;
    int NB = (N + BNODES - 1) >> BSH;
    int quadOK = ((E & 3) == 0) && (((uintptr_t)ei & 15) == 0) && (((uintptr_t)dst & 15) == 0);

    char* ws = (char*)d_ws;
    auto alloc = [&](size_t bytes) {
        void* p = (void*)ws;
        ws += (bytes + 255) / 256 * 256;
        return p;
    };
    float*    dinv      = (float*)alloc((size_t)N * 4);
    int*      bucketCur = (int*)alloc((size_t)NB * 4);
    unsigned* bedges    = (unsigned*)alloc((size_t)NB * CAP * 4);
    int*      offs      = (int*)alloc((size_t)NB * (BNODES + 1) * 4);
    h4*       y2        = (h4*)alloc((size_t)N * DF * 2);
    float*    h         = (float*)alloc((size_t)N * DF * 4);
    float*    psums     = (float*)alloc(64 * DF * 4);   // 16 KB, 256-aligned
    int*      pcnt      = (int*)alloc(64 * 4);

    hipMemsetAsync(bucketCur, 0, (size_t)NB * 4, stream);
    hipMemsetAsync(psums, 0, 64 * DF * 4 + 256, stream);  // sums + cnts contiguous

    if (quadOK) {
        int nq = E >> 2;
        int pblocks = (nq + 2047) / 2048;
        part_kernel<<<pblocks, 256, 0, stream>>>(src, dst, (const int4*)src, (const int4*)dst,
                                                 E, bedges, bucketCur, NB);
    } else {
        part_scalar_kernel<<<1024, 256, 0, stream>>>(src, dst, E, bedges, bucketCur);
    }
    sort_kernel<<<NB, 256, 0, stream>>>(bedges, bucketCur, offs, dinv, N);

    gemm_scale<<<(N + 15) / 16, 256, 0, stream>>>((const float4*)x, (const float4*)W1, dinv,
                                                  y2, N);
    agg_kernel<<<2 * NB, 256, 0, stream>>>(y2, bedges, offs, dinv,
                                           (const float4*)b1, (float4*)h, N);
    gemm_scale<<<(N + 15) / 16, 256, 0, stream>>>((const float4*)h, (const float4*)W2, dinv,
                                                  y2, N);
    agg_kernel<<<2 * NB, 256, 0, stream>>>(y2, bedges, offs, dinv,
                                           (const float4*)b2, (float4*)h, N);

    int waves = (N + 255) / 256;
    pool_kernel<<<(waves + 3) / 4, 256, 0, stream>>>((const float4*)h, batch, psums, pcnt, N);
    final_kernel<<<64, 64, 0, stream>>>(psums, pcnt, Wp, bp, (float*)d_out);
}

// Round 8
// 242.680 us; speedup vs baseline: 6.3021x; 1.0357x over previous
//
#include <hip/hip_runtime.h>
#include <hip/hip_fp16.h>

// TemporalGCN: 2x GCNConv(64->64) + relu, global_mean_pool(64 graphs), linear 64->64.
// R7: all activations fp16 (y AND h; f32 accumulate everywhere), agg uses
// 8-lane groups with 16B h8 loads (half the VMEM instructions of R6),
// merged memset. Pipeline: part -> sort(+dinv) -> gemm1 -> agg1 -> gemm2 ->
// agg2 -> pool -> final.

#define DF 64
#define BSH 7                 // bucket = 128 consecutive dst nodes
#define BNODES 128
#define CAP 4096              // per-bucket edge capacity (mean 2048, >40 sigma)

struct alignas(8)  h4 { __half2 a, b; };        // 4 halves = 8B
struct alignas(16) h8 { __half2 a, b, c, d; };  // 8 halves = 16B

// ---------------- P1: partition edges into dst/128 buckets ----------------

__global__ __launch_bounds__(256) void part_kernel(
        const int* __restrict__ src, const int* __restrict__ dst,
        const int4* __restrict__ src4, const int4* __restrict__ dst4,
        int E, unsigned* __restrict__ bedges, int* __restrict__ bucketCur, int nb) {
    __shared__ int lcnt[1024];
    __shared__ int lbase[1024];
    int tid = threadIdx.x;
    for (int t = tid; t < nb; t += 256) lcnt[t] = 0;
    __syncthreads();
    int nq = E >> 2;
    unsigned packed[32];
    int bkt[32];
    int rk[32];
    int qbase = blockIdx.x * 2048;
#pragma unroll
    for (int c = 0; c < 8; c++) {
        int qi = qbase + c * 256 + tid;
        int4 s = {0, 0, 0, 0}, d = {0, 0, 0, 0};
        bool v = qi < nq;
        if (v) { s = src4[qi]; d = dst4[qi]; }
        packed[4*c+0] = (unsigned)s.x | ((unsigned)(d.x & (BNODES-1)) << 24);
        packed[4*c+1] = (unsigned)s.y | ((unsigned)(d.y & (BNODES-1)) << 24);
        packed[4*c+2] = (unsigned)s.z | ((unsigned)(d.z & (BNODES-1)) << 24);
        packed[4*c+3] = (unsigned)s.w | ((unsigned)(d.w & (BNODES-1)) << 24);
        bkt[4*c+0] = v ? (d.x >> BSH) : -1;
        bkt[4*c+1] = v ? (d.y >> BSH) : -1;
        bkt[4*c+2] = v ? (d.z >> BSH) : -1;
        bkt[4*c+3] = v ? (d.w >> BSH) : -1;
    }
#pragma unroll
    for (int j = 0; j < 32; j++)
        rk[j] = (bkt[j] >= 0) ? atomicAdd(&lcnt[bkt[j]], 1) : 0;
    __syncthreads();
    for (int t = tid; t < nb; t += 256)
        lbase[t] = lcnt[t] ? atomicAdd(&bucketCur[t], lcnt[t]) : 0;
    __syncthreads();
#pragma unroll
    for (int j = 0; j < 32; j++) {
        if (bkt[j] >= 0) {
            int pos = lbase[bkt[j]] + rk[j];
            if (pos < CAP) bedges[(size_t)bkt[j] * CAP + pos] = packed[j];
        }
    }
    if (blockIdx.x == 0 && tid < (E & 3)) {
        int e = nq * 4 + tid;
        int sv = src[e], dv = dst[e];
        int b = dv >> BSH;
        int pos = atomicAdd(&bucketCur[b], 1);
        if (pos < CAP)
            bedges[(size_t)b * CAP + pos] =
                (unsigned)sv | ((unsigned)(dv & (BNODES-1)) << 24);
    }
}

__global__ void part_scalar_kernel(const int* __restrict__ src, const int* __restrict__ dst,
                                   int E, unsigned* __restrict__ bedges,
                                   int* __restrict__ bucketCur) {
    int stride = gridDim.x * blockDim.x;
    for (int e = blockIdx.x * blockDim.x + threadIdx.x; e < E; e += stride) {
        int sv = src[e], dv = dst[e];
        int b = dv >> BSH;
        int pos = atomicAdd(&bucketCur[b], 1);
        if (pos < CAP)
            bedges[(size_t)b * CAP + pos] =
                (unsigned)sv | ((unsigned)(dv & (BNODES-1)) << 24);
    }
}

// ------- P2: per-bucket LDS counting sort (int atomics only) + offsets + dinv -------

__global__ __launch_bounds__(256) void sort_kernel(
        unsigned* __restrict__ bedges, const int* __restrict__ bucketCur,
        int* __restrict__ offs, float* __restrict__ dinv, int N) {
    __shared__ unsigned ein[CAP];
    __shared__ unsigned eout[CAP];
    __shared__ int cnt[BNODES];
    __shared__ int sc[BNODES];
    __shared__ int off[BNODES + 1];
    __shared__ int cur[BNODES];
    int b = blockIdx.x, tid = threadIdx.x;
    int n = min(bucketCur[b], CAP);
    unsigned* gp = bedges + (size_t)b * CAP;
    if (tid < BNODES) cnt[tid] = 0;
    __syncthreads();
    for (int i = tid; i < n; i += 256) {
        unsigned u = gp[i];
        ein[i] = u;
        atomicAdd(&cnt[u >> 24], 1);      // native ds int atomic
    }
    __syncthreads();
    if (tid < BNODES) sc[tid] = cnt[tid];
    __syncthreads();
    for (int d = 1; d < BNODES; d <<= 1) {
        int v = (tid >= d && tid < BNODES) ? sc[tid - d] : 0;
        __syncthreads();
        if (tid < BNODES) sc[tid] += v;
        __syncthreads();
    }
    if (tid < BNODES) {
        off[tid + 1] = sc[tid];
        cur[tid] = sc[tid] - cnt[tid];
        if (tid == 0) off[0] = 0;
    }
    __syncthreads();
    for (int i = tid; i < n; i += 256) {
        unsigned u = ein[i];
        int p = atomicAdd(&cur[u >> 24], 1);
        eout[p] = u;
    }
    __syncthreads();
    for (int i = tid; i < n; i += 256) gp[i] = eout[i];
    if (tid <= BNODES) offs[(size_t)b * (BNODES + 1) + tid] = off[tid];
    int node = (b << BSH) + tid;
    if (tid < BNODES && node < N)
        dinv[node] = 1.0f / sqrtf((float)(cnt[tid] + 1));   // deg = in + self-loop
}

// ---------------- per-layer compute ----------------

// Y[row][c] = (sum_k X[row][k] * W[k][c]) * dinv[row]; f32 input -> fp16 out.
__global__ void gemm_f32in(const float4* __restrict__ X4, const float4* __restrict__ W4,
                           const float* __restrict__ dinv, h4* __restrict__ Y2, int n) {
    __shared__ float4 Wl4[64][16];   // [k][c4]
    __shared__ float Xl[16][68];     // padded: conflict-free broadcast
    int tid = threadIdx.x;
    float4* Wf = &Wl4[0][0];
#pragma unroll
    for (int i = 0; i < 4; i++) {
        int idx = tid + i * 256;     // idx = k*16 + c4
        Wf[idx] = W4[idx];
    }
    int row0 = blockIdx.x * 16;
    int r = tid >> 4, c4 = tid & 15;
    {
        int row = row0 + r;
        float4 v = (row < n) ? X4[(size_t)row * 16 + c4] : float4{0.f, 0.f, 0.f, 0.f};
        Xl[r][c4 * 4 + 0] = v.x;
        Xl[r][c4 * 4 + 1] = v.y;
        Xl[r][c4 * 4 + 2] = v.z;
        Xl[r][c4 * 4 + 3] = v.w;
    }
    __syncthreads();
    float ax = 0.f, ay = 0.f, az = 0.f, aw = 0.f;
#pragma unroll
    for (int k = 0; k < 64; k++) {
        float xv = Xl[r][k];
        float4 w = Wl4[k][c4];
        ax += xv * w.x;
        ay += xv * w.y;
        az += xv * w.z;
        aw += xv * w.w;
    }
    int row = row0 + r;
    if (row < n) {
        float dv = dinv[row];
        h4 o;
        o.a = __floats2half2_rn(ax * dv, ay * dv);
        o.b = __floats2half2_rn(az * dv, aw * dv);
        Y2[(size_t)row * 16 + c4] = o;
    }
}

// same, fp16 input (layer 2: X = h stored as fp16)
__global__ void gemm_f16in(const h4* __restrict__ X2, const float4* __restrict__ W4,
                           const float* __restrict__ dinv, h4* __restrict__ Y2, int n) {
    __shared__ float4 Wl4[64][16];
    __shared__ float Xl[16][68];
    int tid = threadIdx.x;
    float4* Wf = &Wl4[0][0];
#pragma unroll
    for (int i = 0; i < 4; i++) {
        int idx = tid + i * 256;
        Wf[idx] = W4[idx];
    }
    int row0 = blockIdx.x * 16;
    int r = tid >> 4, c4 = tid & 15;
    {
        int row = row0 + r;
        h4 hv = (row < n) ? X2[(size_t)row * 16 + c4] : h4{__half2{0, 0}, __half2{0, 0}};
        float2 va = __half22float2(hv.a), vb = __half22float2(hv.b);
        Xl[r][c4 * 4 + 0] = va.x;
        Xl[r][c4 * 4 + 1] = va.y;
        Xl[r][c4 * 4 + 2] = vb.x;
        Xl[r][c4 * 4 + 3] = vb.y;
    }
    __syncthreads();
    float ax = 0.f, ay = 0.f, az = 0.f, aw = 0.f;
#pragma unroll
    for (int k = 0; k < 64; k++) {
        float xv = Xl[r][k];
        float4 w = Wl4[k][c4];
        ax += xv * w.x;
        ay += xv * w.y;
        az += xv * w.z;
        aw += xv * w.w;
    }
    int row = row0 + r;
    if (row < n) {
        float dv = dinv[row];
        h4 o;
        o.a = __floats2half2_rn(ax * dv, ay * dv);
        o.b = __floats2half2_rn(az * dv, aw * dv);
        Y2[(size_t)row * 16 + c4] = o;
    }
}

#define ACC8(A, w)                                        \
    { float2 _p = __half22float2((w).a);                  \
      A[0] += _p.x; A[1] += _p.y;                         \
      _p = __half22float2((w).b);                         \
      A[2] += _p.x; A[3] += _p.y;                         \
      _p = __half22float2((w).c);                         \
      A[4] += _p.x; A[5] += _p.y;                         \
      _p = __half22float2((w).d);                         \
      A[6] += _p.x; A[7] += _p.y; }

// H[node][:] = relu(dinv*(sum_edges y[src] + y[node]) + b), fp16 out.
// One block per HALF bucket (64 nodes); 256 thr = 32 groups x 8 lanes, h8/lane.
__global__ __launch_bounds__(256) void agg_kernel(
        const h8* __restrict__ Y8, const unsigned* __restrict__ bedges,
        const int* __restrict__ offs, const float* __restrict__ dinv,
        const float* __restrict__ bias, h8* __restrict__ H8, int N) {
    __shared__ unsigned eb[CAP];
    __shared__ int off[65];
    int blk = blockIdx.x;
    int b = blk >> 1, half = blk & 1;
    int tid = threadIdx.x;
    if (tid < 65) off[tid] = offs[(size_t)b * (BNODES + 1) + half * 64 + tid];
    __syncthreads();
    int e0 = off[0];
    int ecnt = off[64] - e0;
    const unsigned* gp = bedges + (size_t)b * CAP + e0;
    for (int i = tid; i < ecnt; i += 256) eb[i] = gp[i];
    __syncthreads();
    int gg = tid >> 3, q = tid & 7;
    float bq[8];
#pragma unroll
    for (int j = 0; j < 8; j++) bq[j] = bias[q * 8 + j];
#pragma unroll
    for (int rr = 0; rr < 2; rr++) {
        int r = gg + rr * 32;
        int s = off[r] - e0, e = off[r + 1] - e0;
        float A0[8], A1[8], A2[8], A3[8];
#pragma unroll
        for (int j = 0; j < 8; j++) { A0[j] = 0.f; A1[j] = 0.f; A2[j] = 0.f; A3[j] = 0.f; }
        int i = s;
        for (; i + 3 < e; i += 4) {
            unsigned u0 = eb[i], u1 = eb[i + 1], u2 = eb[i + 2], u3 = eb[i + 3];
            h8 w0 = Y8[(size_t)(u0 & 0xFFFFFFu) * 8 + q];
            h8 w1 = Y8[(size_t)(u1 & 0xFFFFFFu) * 8 + q];
            h8 w2 = Y8[(size_t)(u2 & 0xFFFFFFu) * 8 + q];
            h8 w3 = Y8[(size_t)(u3 & 0xFFFFFFu) * 8 + q];
            ACC8(A0, w0); ACC8(A1, w1); ACC8(A2, w2); ACC8(A3, w3);
        }
        for (; i < e; i++) {
            unsigned u = eb[i];
            h8 w = Y8[(size_t)(u & 0xFFFFFFu) * 8 + q];
            ACC8(A0, w);
        }
        int node = (b << BSH) + half * 64 + r;
        if (node < N) {
            h8 sv = Y8[(size_t)node * 8 + q];
            float S[8];
            ACC8(A0, sv);
#pragma unroll
            for (int j = 0; j < 8; j++) S[j] = A0[j] + A1[j] + A2[j] + A3[j];
            float dv = dinv[node];
#pragma unroll
            for (int j = 0; j < 8; j++) S[j] = fmaxf(dv * S[j] + bq[j], 0.f);
            h8 o;
            o.a = __floats2half2_rn(S[0], S[1]);
            o.b = __floats2half2_rn(S[2], S[3]);
            o.c = __floats2half2_rn(S[4], S[5]);
            o.d = __floats2half2_rn(S[6], S[7]);
            H8[(size_t)node * 8 + q] = o;
        }
    }
}

// ---------------- pooling + head ----------------

// Each wave owns a 256-row run; 4 lane-groups of 16 take rows step 4; fp16 input.
__global__ void pool_kernel(const h4* __restrict__ H2, const int* __restrict__ batch,
                            float* __restrict__ sums, int* __restrict__ cnts, int n) {
    int gw = (blockIdx.x * blockDim.x + threadIdx.x) >> 6;
    int lane = threadIdx.x & 63;
    int g = lane >> 4, q = lane & 15;
    int start = gw * 256;
    if (start >= n) return;
    int end = min(start + 256, n);
    float ax = 0.f, ay = 0.f, az = 0.f, aw = 0.f;
    int cur = -1, run = 0;
    for (int i = start + g; i < end; i += 4) {
        int b = batch[i];
        if (b != cur) {
            if (run > 0) {
                atomicAdd(&sums[cur * DF + q * 4 + 0], ax);
                atomicAdd(&sums[cur * DF + q * 4 + 1], ay);
                atomicAdd(&sums[cur * DF + q * 4 + 2], az);
                atomicAdd(&sums[cur * DF + q * 4 + 3], aw);
                if (q == 0) atomicAdd(&cnts[cur], run);
            }
            cur = b; run = 0;
            ax = ay = az = aw = 0.f;
        }
        h4 hv = H2[(size_t)i * 16 + q];
        float2 va = __half22float2(hv.a), vb = __half22float2(hv.b);
        ax += va.x; ay += va.y; az += vb.x; aw += vb.y;
        run++;
    }
    if (run > 0) {
        atomicAdd(&sums[cur * DF + q * 4 + 0], ax);
        atomicAdd(&sums[cur * DF + q * 4 + 1], ay);
        atomicAdd(&sums[cur * DF + q * 4 + 2], az);
        atomicAdd(&sums[cur * DF + q * 4 + 3], aw);
        if (q == 0) atomicAdd(&cnts[cur], run);
    }
}

__global__ void final_kernel(const float* __restrict__ sums, const int* __restrict__ cnts,
                             const float* __restrict__ Wp, const float* __restrict__ bp,
                             float* __restrict__ out) {
    int g = blockIdx.x, j = threadIdx.x;
    __shared__ float hg[64];
    float c = fmaxf((float)cnts[g], 1.f);
    hg[j] = sums[g * DF + j] / c;
    __syncthreads();
    float acc = bp[j];
#pragma unroll
    for (int k = 0; k < 64; k++) acc += hg[k] * Wp[k * DF + j];
    out[g * DF + j] = acc;
}

// ---------------- launch ----------------

extern "C" void kernel_launch(void* const* d_in, const int* in_sizes, int n_in,
                              void* d_out, int out_size, void* d_ws, size_t ws_size,
                              hipStream_t stream) {
    const float* x     = (const float*)d_in[0];
    const int*   ei    = (const int*)d_in[1];
    const int*   batch = (const int*)d_in[2];
    const float* W1    = (const float*)d_in[3];
    const float* b1    = (const float*)d_in[4];
    const float* W2    = (const float*)d_in[5];
    const float* b2    = (const float*)d_in[6];
    const float* Wp    = (const float*)d_in[7];
    const float* bp    = (const float*)d_in[8];

    int N = in_sizes[0] / DF;
    int E = in_sizes[1] / 2;
    const int* src = ei;
    const int* dst = ei + E;
    int NB = (N + BNODES - 1) >> BSH;
    int quadOK = ((E & 3) == 0) && (((uintptr_t)ei & 15) == 0) && (((uintptr_t)dst & 15) == 0);

    char* ws = (char*)d_ws;
    auto alloc = [&](size_t bytes) {
        void* p = (void*)ws;
        ws += (bytes + 255) / 256 * 256;
        return p;
    };
    // zero-region: bucketCur | psums | pcnt (single memset)
    size_t zBucketCur = 0;
    size_t zPsums     = ((size_t)NB * 4 + 255) / 256 * 256;
    size_t zPcnt      = zPsums + 64 * DF * 4;
    size_t zTotal     = zPcnt + 256;
    char*     zbase     = (char*)alloc(zTotal);
    int*      bucketCur = (int*)(zbase + zBucketCur);
    float*    psums     = (float*)(zbase + zPsums);
    int*      pcnt      = (int*)(zbase + zPcnt);

    float*    dinv      = (float*)alloc((size_t)N * 4);
    unsigned* bedges    = (unsigned*)alloc((size_t)NB * CAP * 4);
    int*      offs      = (int*)alloc((size_t)NB * (BNODES + 1) * 4);
    h4*       y2        = (h4*)alloc((size_t)N * DF * 2);
    h4*       h2        = (h4*)alloc((size_t)N * DF * 2);

    hipMemsetAsync(zbase, 0, zTotal, stream);

    if (quadOK) {
        int nq = E >> 2;
        int pblocks = (nq + 2047) / 2048;
        part_kernel<<<pblocks, 256, 0, stream>>>(src, dst, (const int4*)src, (const int4*)dst,
                                                 E, bedges, bucketCur, NB);
    } else {
        part_scalar_kernel<<<1024, 256, 0, stream>>>(src, dst, E, bedges, bucketCur);
    }
    sort_kernel<<<NB, 256, 0, stream>>>(bedges, bucketCur, offs, dinv, N);

    gemm_f32in<<<(N + 15) / 16, 256, 0, stream>>>((const float4*)x, (const float4*)W1, dinv,
                                                  y2, N);
    agg_kernel<<<2 * NB, 256, 0, stream>>>((const h8*)y2, bedges, offs, dinv,
                                           b1, (h8*)h2, N);
    gemm_f16in<<<(N + 15) / 16, 256, 0, stream>>>(h2, (const float4*)W2, dinv,
                                                  y2, N);
    agg_kernel<<<2 * NB, 256, 0, stream>>>((const h8*)y2, bedges, offs, dinv,
                                           b2, (h8*)h2, N);

    int waves = (N + 255) / 256;
    pool_kernel<<<(waves + 3) / 4, 256, 0, stream>>>(h2, batch, psums, pcnt, N);
    final_kernel<<<64, 64, 0, stream>>>(psums, pcnt, Wp, bp, (float*)d_out);
}